// Round 8
// baseline (375.487 us; speedup 1.0000x reference)
//
#include <hip/hip_runtime.h>
#include <math.h>

// ---------------------------------------------------------------------------
// ShrdMHAttention: z = (sum_h softmax_causal(rope(xQ) rope(xK)^T) (xV) O_h) * scale
// SEQ=2048, D_MODEL=2048, NH=16, DQK=DV=128.
//
// Precision: q/k proj and QK^T use 2-term fp16 split (hh+hl+lh); v/PV/out are
// single fp16.  absmax 0.03125 vs 0.102 threshold (stable R0-R13).
//
// R14: R13's BM=128 gemm1 reverted (1 block/CU lost sibling overlap, +33us).
// New: k_fused = k_proj + v-gemm in ONE 1024-block launch, interleaved so
// each XCD's dispatch order alternates proj/gemm blocks ((lin>>3)&1) ->
// each CU co-hosts 1 proj + 1 gemm block; uncorrelated barrier phases fill
// each other's staging stalls (m114).  gemm1<0> = R12 design (BM=64, 2/CU).
// k_flash = R12 (T14 reg-staged).  k_pre unchanged.
// ---------------------------------------------------------------------------

typedef _Float16 half_t;
typedef __attribute__((ext_vector_type(8))) _Float16 half8;
typedef __attribute__((ext_vector_type(4))) float f32x4;

#define SEQ   2048
#define DM    2048
#define NHEAD 16

__device__ __forceinline__ f32x4 mfma16(half8 a, half8 b, f32x4 c) {
  return __builtin_amdgcn_mfma_f32_16x16x32_f16(a, b, c, 0, 0, 0);
}

__device__ __forceinline__ void gll16(const half_t* g, half_t* l) {
  __builtin_amdgcn_global_load_lds(
      (const __attribute__((address_space(1))) unsigned int*)g,
      (__attribute__((address_space(3))) unsigned int*)l, 16, 0, 0);
}

// DPP lane-permute within contiguous 16-lane rows (VALU, no LDS pipe).
template <int CTRL>
__device__ __forceinline__ float dppf(float v) {
  int r = __builtin_amdgcn_mov_dpp(__builtin_bit_cast(int, v), CTRL, 0xF, 0xF,
                                   true);
  return __builtin_bit_cast(float, r);
}
__device__ __forceinline__ float red16_max(float v) {
  v = fmaxf(v, dppf<0xB1>(v));   // quad_perm [1,0,3,2]
  v = fmaxf(v, dppf<0x4E>(v));   // quad_perm [2,3,0,1]
  v = fmaxf(v, dppf<0x141>(v));  // row_half_mirror
  v = fmaxf(v, dppf<0x140>(v));  // row_mirror
  return v;
}
__device__ __forceinline__ float red16_sum(float v) {
  v += dppf<0xB1>(v);
  v += dppf<0x4E>(v);
  v += dppf<0x141>(v);
  v += dppf<0x140>(v);
  return v;
}

// ---------------------------------------------------------------------------
// k_pre: one launch for x hi/lo split, q/k/v/o transposes, trig table.
__device__ __forceinline__ void tpose32(const float* __restrict__ in,
                                        half_t* __restrict__ hi,
                                        half_t* __restrict__ lo, int R, int C,
                                        int r0, int c0, float (*tile)[33],
                                        int tid) {
  int tx = tid & 31, ty = tid >> 5;
#pragma unroll
  for (int i = 0; i < 32; i += 8)
    tile[ty + i][tx] = in[(size_t)(r0 + ty + i) * C + c0 + tx];
  __syncthreads();
#pragma unroll
  for (int i = 0; i < 32; i += 8) {
    float v = tile[tx][ty + i];
    half_t h = (half_t)v;
    size_t oidx = (size_t)(c0 + ty + i) * R + r0 + tx;
    hi[oidx] = h;
    if (lo) lo[oidx] = (half_t)(v - (float)h);
  }
}

__global__ __launch_bounds__(256)
void k_pre(const float* __restrict__ x, const float* __restrict__ q,
           const float* __restrict__ k, const float* __restrict__ v,
           const float* __restrict__ o, const float* __restrict__ thetap,
           half_t* __restrict__ Xh, half_t* __restrict__ Xl,
           half_t* __restrict__ WTh, half_t* __restrict__ WTl,
           half_t* __restrict__ VhT, half_t* __restrict__ OT,
           float2* __restrict__ trig) {
  __shared__ float tile[32][33];
  int b = blockIdx.x, tid = threadIdx.x;
  if (b < 4096) {
    int i = b * 256 + tid;
    float4 vv = ((const float4*)x)[i];
    union { half_t h[4]; uint2 u; } H, L;
    H.h[0] = (half_t)vv.x; H.h[1] = (half_t)vv.y;
    H.h[2] = (half_t)vv.z; H.h[3] = (half_t)vv.w;
    L.h[0] = (half_t)(vv.x - (float)H.h[0]);
    L.h[1] = (half_t)(vv.y - (float)H.h[1]);
    L.h[2] = (half_t)(vv.z - (float)H.h[2]);
    L.h[3] = (half_t)(vv.w - (float)H.h[3]);
    *(uint2*)&Xh[(size_t)i * 4] = H.u;
    *(uint2*)&Xl[(size_t)i * 4] = L.u;
  } else if (b < 16384) {
    int j = b - 4096;
    int which = j >> 12, z = (j >> 8) & 15, tb = j & 255;
    int c0 = (tb & 3) * 32, r0 = (tb >> 2) * 32;
    const float* src =
        (which == 0 ? q : which == 1 ? k : v) + (size_t)z * 2048 * 128;
    size_t doff = (size_t)z * 128 * 2048;
    if (which == 0)
      tpose32(src, WTh + doff, WTl + doff, 2048, 128, r0, c0, tile, tid);
    else if (which == 1) {
      size_t koff = (size_t)16 * 128 * 2048 + doff;
      tpose32(src, WTh + koff, WTl + koff, 2048, 128, r0, c0, tile, tid);
    } else
      tpose32(src, VhT + doff, nullptr, 2048, 128, r0, c0, tile, tid);
  } else if (b < 20480) {
    int j = b - 16384;
    int c0 = (j & 63) * 32, r0 = (j >> 6) * 32;
    tpose32(o, OT, nullptr, 2048, 2048, r0, c0, tile, tid);
  } else {
    int idx = (b - 20480) * 256 + tid;  // 0..131071
    int s = idx >> 6, e = idx & 63;
    float th = thetap[0];
    float rate = th * (-(float)e * (1.0f / 64.0f));  // exact e/64
    float rot = (float)s * rate;                     // value numpy takes sin of
    double rev = (double)rot * 0.15915494309189535;  // /(2*pi)
    double fr = rev - rint(rev);
    float thr = (float)(fr * 6.283185307179586);
    float sn = sinf(thr), cs = cosf(thr);
    const float inv4 = 0.2973017787506803f;          // 128^-0.25
    trig[idx] = make_float2(cs * inv4, sn * inv4);
  }
}

// ---------------------------------------------------------------------------
// k_fused: 1024 blocks.  grp=(lin>>3)&1 selects proj(0)/vgemm(1); id =
// (lin>>4)*8+(lin&7) in [0,512).  XCD = lin&7 = id&7 for both -> per-XCD
// alternating proj/gemm fill (1+1 per CU, 64KB LDS each, 128KB/CU).
//
// proj branch (id: y=id>>4, m0=(id&15)*128): R7 split-fp16 3-term + RoPE.
// gemm branch (id -> R12 XCD-compact swizzle): VST = VhT @ Xh^T fp16 out.
__global__ __launch_bounds__(256, 2)
void k_fused(const half_t* __restrict__ Xh, const half_t* __restrict__ Xl,
             const half_t* __restrict__ WTh, const half_t* __restrict__ WTl,
             const float2* __restrict__ trig, half_t* __restrict__ Rh,
             half_t* __restrict__ Rl, const half_t* __restrict__ VhT,
             half_t* __restrict__ VST) {
  __shared__ __align__(16) char smem[65536];
  int lin = blockIdx.x;
  int grp = (lin >> 3) & 1;
  int id = (lin >> 4) * 8 + (lin & 7);  // 0..511, id&7 == lin&7 (XCD)
  int lane = threadIdx.x & 63, wave = threadIdx.x >> 6;
  int l15 = lane & 15, quad = lane >> 4;
  int wm = wave >> 1, wn = wave & 1;

  if (grp == 0) {
    // ----- proj branch (R7 exact) -----
    half_t* sAh = (half_t*)smem;
    half_t* sAl = (half_t*)(smem + 16384);
    half_t* sBh = (half_t*)(smem + 32768);
    half_t* sBl = (half_t*)(smem + 49152);
    int y = id >> 4;
    int m0 = (id & 15) * 128;
    const half_t* wth = WTh + (size_t)y * 128 * DM;
    const half_t* wtl = WTl + (size_t)y * 128 * DM;

    f32x4 acc[4][4];
#pragma unroll
    for (int a = 0; a < 4; ++a)
#pragma unroll
      for (int b = 0; b < 4; ++b) acc[a][b] = (f32x4)0.0f;

    for (int kt = 0; kt < DM / 64; ++kt) {
      int k0 = kt * 64;
#pragma unroll
      for (int i = 0; i < 4; ++i) {
        int c = wave * 4 + i;
        int g = c * 64 + lane;
        int row = g >> 3;
        int lc = (g & 7) ^ (row & 7);
        size_t ro = (size_t)row * DM + k0 + lc * 8;
        gll16(Xh + (size_t)m0 * DM + ro, sAh + c * 512);
        gll16(Xl + (size_t)m0 * DM + ro, sAl + c * 512);
        gll16(wth + ro, sBh + c * 512);
        gll16(wtl + ro, sBl + c * 512);
      }
      __syncthreads();
#pragma unroll
      for (int kk = 0; kk < 2; ++kk) {
        half8 ah[4], al[4], bh[4], bl[4];
#pragma unroll
        for (int t = 0; t < 4; ++t) {
          int ar = wm * 64 + t * 16 + l15;
          int br = wn * 64 + t * 16 + l15;
          int ao = ar * 64 + (((kk * 4 + quad) ^ (ar & 7)) * 8);
          int bo = br * 64 + (((kk * 4 + quad) ^ (br & 7)) * 8);
          ah[t] = *(const half8*)&sAh[ao];
          al[t] = *(const half8*)&sAl[ao];
          bh[t] = *(const half8*)&sBh[bo];
          bl[t] = *(const half8*)&sBl[bo];
        }
#pragma unroll
        for (int im = 0; im < 4; ++im)
#pragma unroll
          for (int in = 0; in < 4; ++in) {
            acc[im][in] = mfma16(ah[im], bh[in], acc[im][in]);
            acc[im][in] = mfma16(ah[im], bl[in], acc[im][in]);
            acc[im][in] = mfma16(al[im], bh[in], acc[im][in]);
          }
      }
      __syncthreads();
    }
    // fused RoPE epilogue
    float* tile = (float*)smem;  // 64 x 132 f32
    size_t ybase = (size_t)y * SEQ * 128;
#pragma unroll
    for (int p = 0; p < 2; ++p) {
      if (p) __syncthreads();
      if (wm == p) {
#pragma unroll
        for (int im = 0; im < 4; ++im)
#pragma unroll
          for (int in = 0; in < 4; ++in)
#pragma unroll
            for (int r = 0; r < 4; ++r)
              tile[(im * 16 + quad * 4 + r) * 132 + wn * 64 + in * 16 + l15] =
                  acc[im][in][r];
      }
      __syncthreads();
      int e = lane;
#pragma unroll 4
      for (int rr = 0; rr < 16; ++rr) {
        int rloc = wave * 16 + rr;
        int s = m0 + p * 64 + rloc;
        float x1 = tile[rloc * 132 + e];
        float x2 = tile[rloc * 132 + 64 + e];
        float2 sc = trig[s * 64 + e];
        float y1 = sc.x * x1 - sc.y * x2;
        float y2 = sc.y * x1 + sc.x * x2;
        half_t h1 = (half_t)y1, h2 = (half_t)y2;
        size_t base = ybase + (size_t)s * 128;
        Rh[base + e] = h1;       Rl[base + e] = (half_t)(y1 - (float)h1);
        Rh[base + 64 + e] = h2;  Rl[base + 64 + e] = (half_t)(y2 - (float)h2);
      }
    }
  } else {
    // ----- v-gemm branch (R12 k_gemm1<1> exact): VST = VhT rows x Xh rows -----
    half_t* sA = (half_t*)smem;               // 64 x 64
    half_t* sB = (half_t*)(smem + 8192);      // 128 x 64
    int xcd = id & 7, slot = id >> 3;         // 8 XCDs x 64 slots
    int bx = (xcd & 3) * 4 + (slot & 3);      // 16 bn tiles
    int by = (xcd >> 2) * 16 + (slot >> 2);   // 32 am tiles
    int am0 = by * 64, bn0 = bx * 128;

    f32x4 acc[2][4];
#pragma unroll
    for (int a = 0; a < 2; ++a)
#pragma unroll
      for (int b = 0; b < 4; ++b) acc[a][b] = (f32x4)0.0f;

    for (int kt = 0; kt < DM / 64; ++kt) {
      int k0 = kt * 64;
#pragma unroll
      for (int i = 0; i < 2; ++i) {
        int g0 = (i * 4 + wave) * 64;
        int g = g0 + lane;
        int row = g >> 3;
        int lc = (g & 7) ^ (row & 7);
        gll16(VhT + (size_t)(am0 + row) * 2048 + k0 + lc * 8, sA + g0 * 8);
      }
#pragma unroll
      for (int i = 0; i < 4; ++i) {
        int g0 = (i * 4 + wave) * 64;
        int g = g0 + lane;
        int row = g >> 3;
        int lc = (g & 7) ^ (row & 7);
        gll16(Xh + (size_t)(bn0 + row) * 2048 + k0 + lc * 8, sB + g0 * 8);
      }
      __syncthreads();
#pragma unroll
      for (int kk = 0; kk < 2; ++kk) {
        half8 ah[2], bh[4];
#pragma unroll
        for (int t = 0; t < 2; ++t) {
          int ar = wm * 32 + t * 16 + l15;
          ah[t] = *(const half8*)&sA[ar * 64 + (((kk * 4 + quad) ^ (ar & 7)) * 8)];
        }
#pragma unroll
        for (int t = 0; t < 4; ++t) {
          int br = wn * 64 + t * 16 + l15;
          bh[t] = *(const half8*)&sB[br * 64 + (((kk * 4 + quad) ^ (br & 7)) * 8)];
        }
#pragma unroll
        for (int im = 0; im < 2; ++im)
#pragma unroll
          for (int in = 0; in < 4; ++in)
            acc[im][in] = mfma16(ah[im], bh[in], acc[im][in]);
      }
      __syncthreads();
    }
#pragma unroll
    for (int im = 0; im < 2; ++im)
#pragma unroll
      for (int in = 0; in < 4; ++in)
#pragma unroll
        for (int r = 0; r < 4; ++r) {
          int row = am0 + wm * 32 + im * 16 + quad * 4 + r;
          int col = bn0 + wn * 64 + in * 16 + l15;
          VST[(size_t)row * 2048 + col] = (half_t)acc[im][in][r];
        }
  }
}

// ---------------------------------------------------------------------------
// Single-term fp16 GEMM (R12 design), BM=64, BN=128, BK=64, 512 blocks=2/CU.
// Used for the out-projection only (fp32 out).
template <int HALF_OUT>
__global__ __launch_bounds__(256)
void k_gemm1(const half_t* __restrict__ A, const half_t* __restrict__ B,
             void* __restrict__ Cv, float scale) {
  __shared__ __align__(16) half_t sA[64 * 64], sB[128 * 64];
  int lin = blockIdx.y * 16 + blockIdx.x;
  int xcd = lin & 7, slot = lin >> 3;          // 8 XCDs x 64 slots
  int bx = (xcd & 3) * 4 + (slot & 3);         // 16 bn tiles
  int by = (xcd >> 2) * 16 + (slot >> 2);      // 32 am tiles
  int am0 = by * 64, bn0 = bx * 128;
  int lane = threadIdx.x & 63, wave = threadIdx.x >> 6;
  int l15 = lane & 15, quad = lane >> 4;
  int wm = wave >> 1, wn = wave & 1;

  f32x4 acc[2][4];
#pragma unroll
  for (int a = 0; a < 2; ++a)
#pragma unroll
    for (int b = 0; b < 4; ++b) acc[a][b] = (f32x4)0.0f;

  for (int kt = 0; kt < DM / 64; ++kt) {
    int k0 = kt * 64;
#pragma unroll
    for (int i = 0; i < 2; ++i) {
      int g0 = (i * 4 + wave) * 64;
      int g = g0 + lane;
      int row = g >> 3;
      int lc = (g & 7) ^ (row & 7);
      gll16(A + (size_t)(am0 + row) * 2048 + k0 + lc * 8, sA + g0 * 8);
    }
#pragma unroll
    for (int i = 0; i < 4; ++i) {
      int g0 = (i * 4 + wave) * 64;
      int g = g0 + lane;
      int row = g >> 3;
      int lc = (g & 7) ^ (row & 7);
      gll16(B + (size_t)(bn0 + row) * 2048 + k0 + lc * 8, sB + g0 * 8);
    }
    __syncthreads();
#pragma unroll
    for (int kk = 0; kk < 2; ++kk) {
      half8 ah[2], bh[4];
#pragma unroll
      for (int t = 0; t < 2; ++t) {
        int ar = wm * 32 + t * 16 + l15;
        ah[t] = *(const half8*)&sA[ar * 64 + (((kk * 4 + quad) ^ (ar & 7)) * 8)];
      }
#pragma unroll
      for (int t = 0; t < 4; ++t) {
        int br = wn * 64 + t * 16 + l15;
        bh[t] = *(const half8*)&sB[br * 64 + (((kk * 4 + quad) ^ (br & 7)) * 8)];
      }
#pragma unroll
      for (int im = 0; im < 2; ++im)
#pragma unroll
        for (int in = 0; in < 4; ++in)
          acc[im][in] = mfma16(ah[im], bh[in], acc[im][in]);
    }
    __syncthreads();
  }
#pragma unroll
  for (int im = 0; im < 2; ++im)
#pragma unroll
    for (int in = 0; in < 4; ++in)
#pragma unroll
      for (int r = 0; r < 4; ++r) {
        int row = am0 + wm * 32 + im * 16 + quad * 4 + r;
        int col = bn0 + wn * 64 + in * 16 + l15;
        if (HALF_OUT)
          ((half_t*)Cv)[(size_t)row * 2048 + col] = (half_t)(acc[im][in][r] * scale);
        else
          ((float*)Cv)[(size_t)row * 2048 + col] = acc[im][in][r] * scale;
      }
}

// ---------------------------------------------------------------------------
// Flash attention, causal.  BM=BN=64, wave owns 16 q-rows.  Grid 512 =
// 32 qtiles x 16 heads, complementary qt pairing.  2 blocks/CU.
// R12: T14 reg-staged K/V prefetch with NAMED registers (macros).
__global__ __launch_bounds__(256, 2)
void k_flash(const half_t* __restrict__ Rh, const half_t* __restrict__ Rl,
             const half_t* __restrict__ VST, half_t* __restrict__ Ybig) {
  int idx = blockIdx.x;
  int h = idx & 15;
  int qt = (idx < 256) ? (31 - (idx >> 4)) : ((idx - 256) >> 4);
  int lane = threadIdx.x & 63, wave = threadIdx.x >> 6;
  int l15 = lane & 15, quad = lane >> 4;

  const half_t* RQh = Rh + (size_t)h * SEQ * 128;
  const half_t* RQl = Rl + (size_t)h * SEQ * 128;
  const half_t* RKh = Rh + (size_t)(NHEAD + h) * SEQ * 128;
  const half_t* RKl = Rl + (size_t)(NHEAD + h) * SEQ * 128;
  const half_t* Vt  = VST + (size_t)h * 128 * SEQ;  // [v][t]

  __shared__ __align__(16) half_t sKh[64 * 128];
  __shared__ __align__(16) half_t sKl[64 * 128];
  __shared__ __align__(16) half_t sVt[128 * 64];
  __shared__ __align__(16) half_t sP[64 * 72];

  int q0 = qt * 64;

  half8 qh[4], ql[4];
#pragma unroll
  for (int kk = 0; kk < 4; ++kk) {
    size_t ad = (size_t)(q0 + wave * 16 + l15) * 128 + kk * 32 + quad * 8;
    qh[kk] = *(const half8*)&RQh[ad];
    ql[kk] = *(const half8*)&RQl[ad];
  }

  // staging lane geometry (dst = c*512 halfs + lane*16B, same as gll16 map)
  int rk_r = (lane >> 4);              // + c*4  -> K row
  int rv_r = (lane >> 3);              // + c*8  -> V row

  // named prefetch registers — never passed by pointer (SROA-safe)
  float4 pk0, pk1, pk2, pk3, pl0, pl1, pl2, pl3, pv0, pv1, pv2, pv3;

#define FL_ONE(i, t0)                                                     \
  {                                                                       \
    int c = wave * 4 + i;                                                 \
    int rk = c * 4 + rk_r;                                                \
    int ck = (lane & 15) ^ (rk & 15);                                     \
    pk##i = *(const float4*)(RKh + (size_t)((t0) + rk) * 128 + ck * 8);   \
    pl##i = *(const float4*)(RKl + (size_t)((t0) + rk) * 128 + ck * 8);   \
    int rv = c * 8 + rv_r;                                                \
    int cv = (lane & 7) ^ (rv & 7);                                       \
    pv##i = *(const float4*)(Vt + (size_t)rv * SEQ + (t0) + cv * 8);      \
  }
#define FLOAD(t0) FL_ONE(0, t0) FL_ONE(1, t0) FL_ONE(2, t0) FL_ONE(3, t0)

#define FW_ONE(i)                                                         \
  {                                                                       \
    int c = wave * 4 + i;                                                 \
    *(float4*)(sKh + c * 512 + lane * 8) = pk##i;                         \
    *(float4*)(sKl + c * 512 + lane * 8) = pl##i;                         \
    *(float4*)(sVt + c * 512 + lane * 8) = pv##i;                         \
  }
#define FWRITE() FW_ONE(0) FW_ONE(1) FW_ONE(2) FW_ONE(3)

  float m_st[4], l_st[4];
  f32x4 oacc[8];
#pragma unroll
  for (int r = 0; r < 4; ++r) { m_st[r] = -INFINITY; l_st[r] = 0.0f; }
#pragma unroll
  for (int iv = 0; iv < 8; ++iv) oacc[iv] = (f32x4)0.0f;

  int nkb = qt + 1;
  FLOAD(0);
  for (int kb = 0; kb < nkb; ++kb) {
    FWRITE();                               // waits vmcnt for its own deps
    if (kb + 1 < nkb) FLOAD((kb + 1) * 64); // prefetch stays in flight
    asm volatile("s_waitcnt lgkmcnt(0)" ::: "memory");  // ds_writes visible
    __builtin_amdgcn_s_barrier();           // all waves wrote their strips

    f32x4 sacc[4];
#pragma unroll
    for (int in = 0; in < 4; ++in) sacc[in] = (f32x4)0.0f;
#pragma unroll
    for (int kk = 0; kk < 4; ++kk)
#pragma unroll
      for (int in = 0; in < 4; ++in) {
        int bo = (in * 16 + l15) * 128 + (((kk * 4 + quad) ^ l15) * 8);
        half8 bh = *(const half8*)&sKh[bo];
        half8 bl = *(const half8*)&sKl[bo];
        sacc[in] = mfma16(qh[kk], bh, sacc[in]);
        sacc[in] = mfma16(qh[kk], bl, sacc[in]);
        sacc[in] = mfma16(ql[kk], bh, sacc[in]);
      }
    if (kb == qt) {  // diagonal block: mask t > s (local indices)
#pragma unroll
      for (int in = 0; in < 4; ++in)
#pragma unroll
        for (int r = 0; r < 4; ++r)
          if (in * 16 + l15 > wave * 16 + quad * 4 + r) sacc[in][r] = -1e30f;
    }
    float alpha[4];
#pragma unroll
    for (int r = 0; r < 4; ++r) {
      float mx = fmaxf(fmaxf(sacc[0][r], sacc[1][r]),
                       fmaxf(sacc[2][r], sacc[3][r]));
      mx = red16_max(mx);
      float mnew = fmaxf(m_st[r], mx);
      alpha[r] = __expf(m_st[r] - mnew);
      float sum = 0.0f;
#pragma unroll
      for (int in = 0; in < 4; ++in) {
        float p = __expf(sacc[in][r] - mnew);
        sacc[in][r] = p;
        sum += p;
      }
      sum = red16_sum(sum);
      l_st[r] = l_st[r] * alpha[r] + sum;
      m_st[r] = mnew;
    }
#pragma unroll
    for (int in = 0; in < 4; ++in)
#pragma unroll
      for (int r = 0; r < 4; ++r)
        sP[(wave * 16 + quad * 4 + r) * 72 + in * 16 + l15] =
            (half_t)sacc[in][r];
#pragma unroll
    for (int iv = 0; iv < 8; ++iv)
#pragma unroll
      for (int r = 0; r < 4; ++r) oacc[iv][r] *= alpha[r];

#pragma unroll
    for (int kk2 = 0; kk2 < 2; ++kk2) {
      half8 pa =
          *(const half8*)&sP[(wave * 16 + l15) * 72 + kk2 * 32 + quad * 8];
#pragma unroll
      for (int iv = 0; iv < 8; ++iv) {
        half8 vb = *(const half8*)&sVt[(iv * 16 + l15) * 64 +
                                       (((kk2 * 4 + quad) ^ (l15 & 7)) * 8)];
        oacc[iv] = mfma16(pa, vb, oacc[iv]);
      }
    }
    asm volatile("" ::: "memory");         // LDS reads consumed (WAR)
    __builtin_amdgcn_s_barrier();
  }
  float invl[4];
#pragma unroll
  for (int r = 0; r < 4; ++r) invl[r] = 1.0f / l_st[r];
#pragma unroll
  for (int iv = 0; iv < 8; ++iv)
#pragma unroll
    for (int r = 0; r < 4; ++r) {
      int row = q0 + wave * 16 + quad * 4 + r;
      int col = h * 128 + iv * 16 + l15;
      Ybig[(size_t)row * 2048 + col] = (half_t)(oacc[iv][r] * invl[r]);
    }
#undef FL_ONE
#undef FLOAD
#undef FW_ONE
#undef FWRITE
}

// ---------------------------------------------------------------------------
extern "C" void kernel_launch(void* const* d_in, const int* in_sizes, int n_in,
                              void* d_out, int out_size, void* d_ws,
                              size_t ws_size, hipStream_t stream) {
  const float* x = (const float*)d_in[0];
  const float* q = (const float*)d_in[1];
  const float* k = (const float*)d_in[2];
  const float* v = (const float*)d_in[3];
  const float* o = (const float*)d_in[4];
  const float* theta = (const float*)d_in[5];
  float* out = (float*)d_out;

  char* ws = (char*)d_ws;
  const size_t HB = (size_t)2048 * 2048 * 2;  // 8 MiB
  half_t* Xh   = (half_t*)(ws);            // [2048 s][2048 d]
  half_t* Xl   = (half_t*)(ws + HB);
  half_t* WTh  = (half_t*)(ws + 2 * HB);   // [2][16][128 e][2048 d] (2 HB)
  half_t* WTl  = (half_t*)(ws + 4 * HB);   // (2 HB)
  half_t* VhT  = (half_t*)(ws + 6 * HB);   // [16][128 v][2048 d]
  half_t* OT   = (half_t*)(ws + 7 * HB);   // [2048 d][2048 hv]
  half_t* Rh   = (half_t*)(ws + 8 * HB);   // [2][16][2048 s][128 e] (2 HB)
  half_t* Rl   = (half_t*)(ws + 10 * HB);  // (2 HB)
  float2* trig = (float2*)(ws + 12 * HB);  // 1 MB
  half_t* VST  = (half_t*)(ws + 13 * HB);  // [16][128 v][2048 t] fp16
  half_t* Ybig = (half_t*)(ws + 3 * HB);   // overlay WTh upper half (dead
                                           // after k_fused)

  // 1. preprocessing: split, 4 transposes, trig table (one launch)
  k_pre<<<20992, 256, 0, stream>>>(x, q, k, v, o, theta, Xh, Xl, WTh, WTl,
                                   VhT, OT, trig);
  // 2+3. fused: q/k projections + rope -> Rh/Rl  ||  v projection -> VST
  k_fused<<<1024, 256, 0, stream>>>(Xh, Xl, WTh, WTl, trig, Rh, Rl, VhT, VST);
  // 4. flash attention -> Ybig [s][h*128+v] fp16
  k_flash<<<512, 256, 0, stream>>>(Rh, Rl, VST, Ybig);
  // 5. out projection: z = Ybig @ OT * (1/2048) -> fp32
  k_gemm1<0><<<dim3(16, 32), 256, 0, stream>>>(Ybig, OT, out, 1.0f / 2048.0f);
}

// Round 9
// 337.900 us; speedup vs baseline: 1.1112x; 1.1112x over previous
//
#include <hip/hip_runtime.h>
#include <math.h>

// ---------------------------------------------------------------------------
// ShrdMHAttention: z = (sum_h softmax_causal(rope(xQ) rope(xK)^T) (xV) O_h) * scale
// SEQ=2048, D_MODEL=2048, NH=16, DQK=DV=128.
//
// Precision: q/k proj and QK^T use 2-term fp16 split (hh+hl+lh); v/PV/out are
// single fp16.  absmax 0.03125 vs 0.102 threshold (stable R0-R14).
// NOTE: all 3 split terms are numerically load-bearing (scores sigma~2000
// pre-softmax; single-fp16 QK/proj -> e^{+-1..2} softmax corruption).
//
// R15 = R12 (best verified, 339.6us) + T5 s_setprio around k_flash MFMA
// clusters only (attn regime: independent blocks, uncorrelated phases —
// m191 +4-7%; GEMMs left alone per m190 null/negative).
// Failed-lever ledger: R8/R9 2-phase pipelining (regime-gated null),
// R13 BM=128 gemm (1 blk/CU lost sibling overlap), R14 proj||vgemm fusion
// (2 scheduling generations + merged regalloc, -36us).
// ---------------------------------------------------------------------------

typedef _Float16 half_t;
typedef __attribute__((ext_vector_type(8))) _Float16 half8;
typedef __attribute__((ext_vector_type(4))) float f32x4;

#define SEQ   2048
#define DM    2048
#define NHEAD 16

__device__ __forceinline__ f32x4 mfma16(half8 a, half8 b, f32x4 c) {
  return __builtin_amdgcn_mfma_f32_16x16x32_f16(a, b, c, 0, 0, 0);
}

__device__ __forceinline__ void gll16(const half_t* g, half_t* l) {
  __builtin_amdgcn_global_load_lds(
      (const __attribute__((address_space(1))) unsigned int*)g,
      (__attribute__((address_space(3))) unsigned int*)l, 16, 0, 0);
}

// DPP lane-permute within contiguous 16-lane rows (VALU, no LDS pipe).
template <int CTRL>
__device__ __forceinline__ float dppf(float v) {
  int r = __builtin_amdgcn_mov_dpp(__builtin_bit_cast(int, v), CTRL, 0xF, 0xF,
                                   true);
  return __builtin_bit_cast(float, r);
}
__device__ __forceinline__ float red16_max(float v) {
  v = fmaxf(v, dppf<0xB1>(v));   // quad_perm [1,0,3,2]
  v = fmaxf(v, dppf<0x4E>(v));   // quad_perm [2,3,0,1]
  v = fmaxf(v, dppf<0x141>(v));  // row_half_mirror
  v = fmaxf(v, dppf<0x140>(v));  // row_mirror
  return v;
}
__device__ __forceinline__ float red16_sum(float v) {
  v += dppf<0xB1>(v);
  v += dppf<0x4E>(v);
  v += dppf<0x141>(v);
  v += dppf<0x140>(v);
  return v;
}

// ---------------------------------------------------------------------------
// k_pre: one launch for x hi/lo split, q/k/v/o transposes, trig table.
__device__ __forceinline__ void tpose32(const float* __restrict__ in,
                                        half_t* __restrict__ hi,
                                        half_t* __restrict__ lo, int R, int C,
                                        int r0, int c0, float (*tile)[33],
                                        int tid) {
  int tx = tid & 31, ty = tid >> 5;
#pragma unroll
  for (int i = 0; i < 32; i += 8)
    tile[ty + i][tx] = in[(size_t)(r0 + ty + i) * C + c0 + tx];
  __syncthreads();
#pragma unroll
  for (int i = 0; i < 32; i += 8) {
    float v = tile[tx][ty + i];
    half_t h = (half_t)v;
    size_t oidx = (size_t)(c0 + ty + i) * R + r0 + tx;
    hi[oidx] = h;
    if (lo) lo[oidx] = (half_t)(v - (float)h);
  }
}

__global__ __launch_bounds__(256)
void k_pre(const float* __restrict__ x, const float* __restrict__ q,
           const float* __restrict__ k, const float* __restrict__ v,
           const float* __restrict__ o, const float* __restrict__ thetap,
           half_t* __restrict__ Xh, half_t* __restrict__ Xl,
           half_t* __restrict__ WTh, half_t* __restrict__ WTl,
           half_t* __restrict__ VhT, half_t* __restrict__ OT,
           float2* __restrict__ trig) {
  __shared__ float tile[32][33];
  int b = blockIdx.x, tid = threadIdx.x;
  if (b < 4096) {
    int i = b * 256 + tid;
    float4 vv = ((const float4*)x)[i];
    union { half_t h[4]; uint2 u; } H, L;
    H.h[0] = (half_t)vv.x; H.h[1] = (half_t)vv.y;
    H.h[2] = (half_t)vv.z; H.h[3] = (half_t)vv.w;
    L.h[0] = (half_t)(vv.x - (float)H.h[0]);
    L.h[1] = (half_t)(vv.y - (float)H.h[1]);
    L.h[2] = (half_t)(vv.z - (float)H.h[2]);
    L.h[3] = (half_t)(vv.w - (float)H.h[3]);
    *(uint2*)&Xh[(size_t)i * 4] = H.u;
    *(uint2*)&Xl[(size_t)i * 4] = L.u;
  } else if (b < 16384) {
    int j = b - 4096;
    int which = j >> 12, z = (j >> 8) & 15, tb = j & 255;
    int c0 = (tb & 3) * 32, r0 = (tb >> 2) * 32;
    const float* src =
        (which == 0 ? q : which == 1 ? k : v) + (size_t)z * 2048 * 128;
    size_t doff = (size_t)z * 128 * 2048;
    if (which == 0)
      tpose32(src, WTh + doff, WTl + doff, 2048, 128, r0, c0, tile, tid);
    else if (which == 1) {
      size_t koff = (size_t)16 * 128 * 2048 + doff;
      tpose32(src, WTh + koff, WTl + koff, 2048, 128, r0, c0, tile, tid);
    } else
      tpose32(src, VhT + doff, nullptr, 2048, 128, r0, c0, tile, tid);
  } else if (b < 20480) {
    int j = b - 16384;
    int c0 = (j & 63) * 32, r0 = (j >> 6) * 32;
    tpose32(o, OT, nullptr, 2048, 2048, r0, c0, tile, tid);
  } else {
    int idx = (b - 20480) * 256 + tid;  // 0..131071
    int s = idx >> 6, e = idx & 63;
    float th = thetap[0];
    float rate = th * (-(float)e * (1.0f / 64.0f));  // exact e/64
    float rot = (float)s * rate;                     // value numpy takes sin of
    double rev = (double)rot * 0.15915494309189535;  // /(2*pi)
    double fr = rev - rint(rev);
    float thr = (float)(fr * 6.283185307179586);
    float sn = sinf(thr), cs = cosf(thr);
    const float inv4 = 0.2973017787506803f;          // 128^-0.25
    trig[idx] = make_float2(cs * inv4, sn * inv4);
  }
}

// ---------------------------------------------------------------------------
// Split-fp16 projection (3-term) with fused RoPE epilogue.  BM=BN=128, BK=64.
// (R7 design: single-buffer 2-phase — measured 89.6us, MfmaUtil 51.7%.)
__global__ __launch_bounds__(256, 2)
void k_proj(const half_t* __restrict__ Xh, const half_t* __restrict__ Xl,
            const half_t* __restrict__ WTh, const half_t* __restrict__ WTl,
            const float2* __restrict__ trig, half_t* __restrict__ Rh,
            half_t* __restrict__ Rl) {
  __shared__ __align__(16) char smem[65536];
  half_t* sAh = (half_t*)smem;
  half_t* sAl = (half_t*)(smem + 16384);
  half_t* sBh = (half_t*)(smem + 32768);
  half_t* sBl = (half_t*)(smem + 49152);
  int y = blockIdx.y;
  int m0 = blockIdx.x * 128;
  const half_t* wth = WTh + (size_t)y * 128 * DM;
  const half_t* wtl = WTl + (size_t)y * 128 * DM;
  int lane = threadIdx.x & 63, wave = threadIdx.x >> 6;
  int l15 = lane & 15, quad = lane >> 4;
  int wm = wave >> 1, wn = wave & 1;

  f32x4 acc[4][4];
#pragma unroll
  for (int a = 0; a < 4; ++a)
#pragma unroll
    for (int b = 0; b < 4; ++b) acc[a][b] = (f32x4)0.0f;

  for (int kt = 0; kt < DM / 64; ++kt) {
    int k0 = kt * 64;
#pragma unroll
    for (int i = 0; i < 4; ++i) {
      int c = wave * 4 + i;
      int g = c * 64 + lane;
      int row = g >> 3;
      int lc = (g & 7) ^ (row & 7);
      size_t ro = (size_t)row * DM + k0 + lc * 8;
      gll16(Xh + (size_t)m0 * DM + ro, sAh + c * 512);
      gll16(Xl + (size_t)m0 * DM + ro, sAl + c * 512);
      gll16(wth + ro, sBh + c * 512);
      gll16(wtl + ro, sBl + c * 512);
    }
    __syncthreads();
#pragma unroll
    for (int kk = 0; kk < 2; ++kk) {
      half8 ah[4], al[4], bh[4], bl[4];
#pragma unroll
      for (int t = 0; t < 4; ++t) {
        int ar = wm * 64 + t * 16 + l15;
        int br = wn * 64 + t * 16 + l15;
        int ao = ar * 64 + (((kk * 4 + quad) ^ (ar & 7)) * 8);
        int bo = br * 64 + (((kk * 4 + quad) ^ (br & 7)) * 8);
        ah[t] = *(const half8*)&sAh[ao];
        al[t] = *(const half8*)&sAl[ao];
        bh[t] = *(const half8*)&sBh[bo];
        bl[t] = *(const half8*)&sBl[bo];
      }
#pragma unroll
      for (int im = 0; im < 4; ++im)
#pragma unroll
        for (int in = 0; in < 4; ++in) {
          acc[im][in] = mfma16(ah[im], bh[in], acc[im][in]);
          acc[im][in] = mfma16(ah[im], bl[in], acc[im][in]);
          acc[im][in] = mfma16(al[im], bh[in], acc[im][in]);
        }
    }
    __syncthreads();
  }
  // fused RoPE epilogue
  float* tile = (float*)smem;  // 64 x 132 f32
  size_t ybase = (size_t)y * SEQ * 128;
#pragma unroll
  for (int p = 0; p < 2; ++p) {
    if (p) __syncthreads();
    if (wm == p) {
#pragma unroll
      for (int im = 0; im < 4; ++im)
#pragma unroll
        for (int in = 0; in < 4; ++in)
#pragma unroll
          for (int r = 0; r < 4; ++r)
            tile[(im * 16 + quad * 4 + r) * 132 + wn * 64 + in * 16 + l15] =
                acc[im][in][r];
    }
    __syncthreads();
    int e = lane;
#pragma unroll 4
    for (int rr = 0; rr < 16; ++rr) {
      int rloc = wave * 16 + rr;
      int s = m0 + p * 64 + rloc;
      float x1 = tile[rloc * 132 + e];
      float x2 = tile[rloc * 132 + 64 + e];
      float2 sc = trig[s * 64 + e];
      float y1 = sc.x * x1 - sc.y * x2;
      float y2 = sc.y * x1 + sc.x * x2;
      half_t h1 = (half_t)y1, h2 = (half_t)y2;
      size_t base = ybase + (size_t)s * 128;
      Rh[base + e] = h1;       Rl[base + e] = (half_t)(y1 - (float)h1);
      Rh[base + 64 + e] = h2;  Rl[base + 64 + e] = (half_t)(y2 - (float)h2);
    }
  }
}

// ---------------------------------------------------------------------------
// Single-term fp16 GEMM, BM=64, BN=128, BK=64, 512 blocks = 2/CU.
// XCD-compact swizzle: XCD x owns bn in [ (x&3)*4, +4 ), am in [ (x>>2)*16, +16 )
// -> per-XCD fetch = 4 B-strips + 16 A-strips = 6 MB.
template <int HALF_OUT>
__global__ __launch_bounds__(256)
void k_gemm1(const half_t* __restrict__ A, const half_t* __restrict__ B,
             void* __restrict__ Cv, float scale) {
  __shared__ __align__(16) half_t sA[64 * 64], sB[128 * 64];
  int lin = blockIdx.y * 16 + blockIdx.x;
  int xcd = lin & 7, slot = lin >> 3;          // 8 XCDs x 64 slots
  int bx = (xcd & 3) * 4 + (slot & 3);         // 16 bn tiles
  int by = (xcd >> 2) * 16 + (slot >> 2);      // 32 am tiles
  int am0 = by * 64, bn0 = bx * 128;
  int lane = threadIdx.x & 63, wave = threadIdx.x >> 6;
  int l15 = lane & 15, quad = lane >> 4;
  int wm = wave >> 1, wn = wave & 1;

  f32x4 acc[2][4];
#pragma unroll
  for (int a = 0; a < 2; ++a)
#pragma unroll
    for (int b = 0; b < 4; ++b) acc[a][b] = (f32x4)0.0f;

  for (int kt = 0; kt < DM / 64; ++kt) {
    int k0 = kt * 64;
#pragma unroll
    for (int i = 0; i < 2; ++i) {
      int g0 = (i * 4 + wave) * 64;
      int g = g0 + lane;
      int row = g >> 3;
      int lc = (g & 7) ^ (row & 7);
      gll16(A + (size_t)(am0 + row) * 2048 + k0 + lc * 8, sA + g0 * 8);
    }
#pragma unroll
    for (int i = 0; i < 4; ++i) {
      int g0 = (i * 4 + wave) * 64;
      int g = g0 + lane;
      int row = g >> 3;
      int lc = (g & 7) ^ (row & 7);
      gll16(B + (size_t)(bn0 + row) * 2048 + k0 + lc * 8, sB + g0 * 8);
    }
    __syncthreads();
#pragma unroll
    for (int kk = 0; kk < 2; ++kk) {
      half8 ah[2], bh[4];
#pragma unroll
      for (int t = 0; t < 2; ++t) {
        int ar = wm * 32 + t * 16 + l15;
        ah[t] = *(const half8*)&sA[ar * 64 + (((kk * 4 + quad) ^ (ar & 7)) * 8)];
      }
#pragma unroll
      for (int t = 0; t < 4; ++t) {
        int br = wn * 64 + t * 16 + l15;
        bh[t] = *(const half8*)&sB[br * 64 + (((kk * 4 + quad) ^ (br & 7)) * 8)];
      }
#pragma unroll
      for (int im = 0; im < 2; ++im)
#pragma unroll
        for (int in = 0; in < 4; ++in)
          acc[im][in] = mfma16(ah[im], bh[in], acc[im][in]);
    }
    __syncthreads();
  }
#pragma unroll
  for (int im = 0; im < 2; ++im)
#pragma unroll
    for (int in = 0; in < 4; ++in)
#pragma unroll
      for (int r = 0; r < 4; ++r) {
        int row = am0 + wm * 32 + im * 16 + quad * 4 + r;
        int col = bn0 + wn * 64 + in * 16 + l15;
        if (HALF_OUT)
          ((half_t*)Cv)[(size_t)row * 2048 + col] = (half_t)(acc[im][in][r] * scale);
        else
          ((float*)Cv)[(size_t)row * 2048 + col] = acc[im][in][r] * scale;
      }
}

// ---------------------------------------------------------------------------
// Flash attention, causal.  BM=BN=64, wave owns 16 q-rows.  Grid 512 =
// 32 qtiles x 16 heads, complementary qt pairing.  2 blocks/CU.
// R12: T14 reg-staged K/V prefetch with NAMED registers (macros).
// R15: + T5 s_setprio(1) around QK^T and PV MFMA clusters (independent
// blocks -> uncorrelated phases -> scheduler arbitration pays, m191).
__global__ __launch_bounds__(256, 2)
void k_flash(const half_t* __restrict__ Rh, const half_t* __restrict__ Rl,
             const half_t* __restrict__ VST, half_t* __restrict__ Ybig) {
  int idx = blockIdx.x;
  int h = idx & 15;
  int qt = (idx < 256) ? (31 - (idx >> 4)) : ((idx - 256) >> 4);
  int lane = threadIdx.x & 63, wave = threadIdx.x >> 6;
  int l15 = lane & 15, quad = lane >> 4;

  const half_t* RQh = Rh + (size_t)h * SEQ * 128;
  const half_t* RQl = Rl + (size_t)h * SEQ * 128;
  const half_t* RKh = Rh + (size_t)(NHEAD + h) * SEQ * 128;
  const half_t* RKl = Rl + (size_t)(NHEAD + h) * SEQ * 128;
  const half_t* Vt  = VST + (size_t)h * 128 * SEQ;  // [v][t]

  __shared__ __align__(16) half_t sKh[64 * 128];
  __shared__ __align__(16) half_t sKl[64 * 128];
  __shared__ __align__(16) half_t sVt[128 * 64];
  __shared__ __align__(16) half_t sP[64 * 72];

  int q0 = qt * 64;

  half8 qh[4], ql[4];
#pragma unroll
  for (int kk = 0; kk < 4; ++kk) {
    size_t ad = (size_t)(q0 + wave * 16 + l15) * 128 + kk * 32 + quad * 8;
    qh[kk] = *(const half8*)&RQh[ad];
    ql[kk] = *(const half8*)&RQl[ad];
  }

  // staging lane geometry (dst = c*512 halfs + lane*16B, same as gll16 map)
  int rk_r = (lane >> 4);              // + c*4  -> K row
  int rv_r = (lane >> 3);              // + c*8  -> V row

  // named prefetch registers — never passed by pointer (SROA-safe)
  float4 pk0, pk1, pk2, pk3, pl0, pl1, pl2, pl3, pv0, pv1, pv2, pv3;

#define FL_ONE(i, t0)                                                     \
  {                                                                       \
    int c = wave * 4 + i;                                                 \
    int rk = c * 4 + rk_r;                                                \
    int ck = (lane & 15) ^ (rk & 15);                                     \
    pk##i = *(const float4*)(RKh + (size_t)((t0) + rk) * 128 + ck * 8);   \
    pl##i = *(const float4*)(RKl + (size_t)((t0) + rk) * 128 + ck * 8);   \
    int rv = c * 8 + rv_r;                                                \
    int cv = (lane & 7) ^ (rv & 7);                                       \
    pv##i = *(const float4*)(Vt + (size_t)rv * SEQ + (t0) + cv * 8);      \
  }
#define FLOAD(t0) FL_ONE(0, t0) FL_ONE(1, t0) FL_ONE(2, t0) FL_ONE(3, t0)

#define FW_ONE(i)                                                         \
  {                                                                       \
    int c = wave * 4 + i;                                                 \
    *(float4*)(sKh + c * 512 + lane * 8) = pk##i;                         \
    *(float4*)(sKl + c * 512 + lane * 8) = pl##i;                         \
    *(float4*)(sVt + c * 512 + lane * 8) = pv##i;                         \
  }
#define FWRITE() FW_ONE(0) FW_ONE(1) FW_ONE(2) FW_ONE(3)

  float m_st[4], l_st[4];
  f32x4 oacc[8];
#pragma unroll
  for (int r = 0; r < 4; ++r) { m_st[r] = -INFINITY; l_st[r] = 0.0f; }
#pragma unroll
  for (int iv = 0; iv < 8; ++iv) oacc[iv] = (f32x4)0.0f;

  int nkb = qt + 1;
  FLOAD(0);
  for (int kb = 0; kb < nkb; ++kb) {
    FWRITE();                               // waits vmcnt for its own deps
    if (kb + 1 < nkb) FLOAD((kb + 1) * 64); // prefetch stays in flight
    asm volatile("s_waitcnt lgkmcnt(0)" ::: "memory");  // ds_writes visible
    __builtin_amdgcn_s_barrier();           // all waves wrote their strips

    f32x4 sacc[4];
#pragma unroll
    for (int in = 0; in < 4; ++in) sacc[in] = (f32x4)0.0f;
    __builtin_amdgcn_s_setprio(1);          // T5: favor MFMA wave
#pragma unroll
    for (int kk = 0; kk < 4; ++kk)
#pragma unroll
      for (int in = 0; in < 4; ++in) {
        int bo = (in * 16 + l15) * 128 + (((kk * 4 + quad) ^ l15) * 8);
        half8 bh = *(const half8*)&sKh[bo];
        half8 bl = *(const half8*)&sKl[bo];
        sacc[in] = mfma16(qh[kk], bh, sacc[in]);
        sacc[in] = mfma16(qh[kk], bl, sacc[in]);
        sacc[in] = mfma16(ql[kk], bh, sacc[in]);
      }
    __builtin_amdgcn_s_setprio(0);
    if (kb == qt) {  // diagonal block: mask t > s (local indices)
#pragma unroll
      for (int in = 0; in < 4; ++in)
#pragma unroll
        for (int r = 0; r < 4; ++r)
          if (in * 16 + l15 > wave * 16 + quad * 4 + r) sacc[in][r] = -1e30f;
    }
    float alpha[4];
#pragma unroll
    for (int r = 0; r < 4; ++r) {
      float mx = fmaxf(fmaxf(sacc[0][r], sacc[1][r]),
                       fmaxf(sacc[2][r], sacc[3][r]));
      mx = red16_max(mx);
      float mnew = fmaxf(m_st[r], mx);
      alpha[r] = __expf(m_st[r] - mnew);
      float sum = 0.0f;
#pragma unroll
      for (int in = 0; in < 4; ++in) {
        float p = __expf(sacc[in][r] - mnew);
        sacc[in][r] = p;
        sum += p;
      }
      sum = red16_sum(sum);
      l_st[r] = l_st[r] * alpha[r] + sum;
      m_st[r] = mnew;
    }
#pragma unroll
    for (int in = 0; in < 4; ++in)
#pragma unroll
      for (int r = 0; r < 4; ++r)
        sP[(wave * 16 + quad * 4 + r) * 72 + in * 16 + l15] =
            (half_t)sacc[in][r];
#pragma unroll
    for (int iv = 0; iv < 8; ++iv)
#pragma unroll
      for (int r = 0; r < 4; ++r) oacc[iv][r] *= alpha[r];

    __builtin_amdgcn_s_setprio(1);          // T5: favor MFMA wave (PV)
#pragma unroll
    for (int kk2 = 0; kk2 < 2; ++kk2) {
      half8 pa =
          *(const half8*)&sP[(wave * 16 + l15) * 72 + kk2 * 32 + quad * 8];
#pragma unroll
      for (int iv = 0; iv < 8; ++iv) {
        half8 vb = *(const half8*)&sVt[(iv * 16 + l15) * 64 +
                                       (((kk2 * 4 + quad) ^ (l15 & 7)) * 8)];
        oacc[iv] = mfma16(pa, vb, oacc[iv]);
      }
    }
    __builtin_amdgcn_s_setprio(0);
    asm volatile("" ::: "memory");         // LDS reads consumed (WAR)
    __builtin_amdgcn_s_barrier();
  }
  float invl[4];
#pragma unroll
  for (int r = 0; r < 4; ++r) invl[r] = 1.0f / l_st[r];
#pragma unroll
  for (int iv = 0; iv < 8; ++iv)
#pragma unroll
    for (int r = 0; r < 4; ++r) {
      int row = q0 + wave * 16 + quad * 4 + r;
      int col = h * 128 + iv * 16 + l15;
      Ybig[(size_t)row * 2048 + col] = (half_t)(oacc[iv][r] * invl[r]);
    }
#undef FL_ONE
#undef FLOAD
#undef FW_ONE
#undef FWRITE
}

// ---------------------------------------------------------------------------
extern "C" void kernel_launch(void* const* d_in, const int* in_sizes, int n_in,
                              void* d_out, int out_size, void* d_ws,
                              size_t ws_size, hipStream_t stream) {
  const float* x = (const float*)d_in[0];
  const float* q = (const float*)d_in[1];
  const float* k = (const float*)d_in[2];
  const float* v = (const float*)d_in[3];
  const float* o = (const float*)d_in[4];
  const float* theta = (const float*)d_in[5];
  float* out = (float*)d_out;

  char* ws = (char*)d_ws;
  const size_t HB = (size_t)2048 * 2048 * 2;  // 8 MiB
  half_t* Xh   = (half_t*)(ws);            // [2048 s][2048 d]
  half_t* Xl   = (half_t*)(ws + HB);
  half_t* WTh  = (half_t*)(ws + 2 * HB);   // [2][16][128 e][2048 d] (2 HB)
  half_t* WTl  = (half_t*)(ws + 4 * HB);   // (2 HB)
  half_t* VhT  = (half_t*)(ws + 6 * HB);   // [16][128 v][2048 d]
  half_t* OT   = (half_t*)(ws + 7 * HB);   // [2048 d][2048 hv]
  half_t* Rh   = (half_t*)(ws + 8 * HB);   // [2][16][2048 s][128 e] (2 HB)
  half_t* Rl   = (half_t*)(ws + 10 * HB);  // (2 HB)
  float2* trig = (float2*)(ws + 12 * HB);  // 1 MB
  half_t* VST  = (half_t*)(ws + 2 * HB);   // overlay WTh (dead after proj)
  half_t* Ybig = (half_t*)(ws + 3 * HB);   // overlay WTh upper half

  // 1. preprocessing: split, 4 transposes, trig table (one launch)
  k_pre<<<20992, 256, 0, stream>>>(x, q, k, v, o, theta, Xh, Xl, WTh, WTl,
                                   VhT, OT, trig);
  // 2. q/k projections + fused rope -> Rh/Rl
  k_proj<<<dim3(16, 32), 256, 0, stream>>>(Xh, Xl, WTh, WTl, trig, Rh, Rl);
  // 3. v projection -> VS^T [h][v][t] fp16
  k_gemm1<1><<<dim3(16, 32), 256, 0, stream>>>(VhT, Xh, VST, 1.0f);
  // 4. flash attention -> Ybig [s][h*128+v] fp16
  k_flash<<<512, 256, 0, stream>>>(Rh, Rl, VST, Ybig);
  // 5. out projection: z = Ybig @ OT * (1/2048) -> fp32
  k_gemm1<0><<<dim3(16, 32), 256, 0, stream>>>(Ybig, OT, out, 1.0f / 2048.0f);
}